// Round 2
// baseline (26459.293 us; speedup 1.0000x reference)
//
#include <hip/hip_runtime.h>
#include <stdint.h>

typedef __attribute__((ext_vector_type(8))) short short8;
typedef __attribute__((ext_vector_type(4))) float floatx4;

#define DI __device__ __forceinline__

// Problem dims
constexpr int BB = 64;          // batch
constexpr int SS = 512;         // seq len
constexpr int II = 1024;        // input size
constexpr int HH = 1024;        // hidden size
constexpr int MM = BB * SS;     // 32768 GEMM rows
constexpr int NBLK = 64;        // recurrence blocks

DI unsigned short f2bf(float f) {
  union { float f; unsigned int u; } v; v.f = f;
  unsigned int u = v.u;
  return (unsigned short)((u + 0x7FFFu + ((u >> 16) & 1u)) >> 16);  // RNE
}
DI float bf2f(unsigned short u) {
  union { unsigned int u; float f; } v; v.u = ((unsigned int)u) << 16;
  return v.f;
}
DI float sigmoidf_(float x) { return 1.0f / (1.0f + __expf(-x)); }
DI float tanhf_(float x)    { return 2.0f / (1.0f + __expf(-2.0f * x)) - 1.0f; }

DI void gload_lds16(const unsigned short* g, unsigned short* l) {
  typedef __attribute__((address_space(1))) const void gv_t;
  typedef __attribute__((address_space(3))) void lv_t;
  __builtin_amdgcn_global_load_lds((gv_t*)(uintptr_t)g, (lv_t*)(uintptr_t)l, 16, 0, 0);
}

// Monotonic-generation grid barrier. bar[0]=arrive count, bar[1]=release gen.
// Zeroed each launch by k_cast_x (stream-ordered before the recurrence).
DI void grid_barrier(int* bar, int gen) {
  __syncthreads();
  if (threadIdx.x == 0) {
    __threadfence();  // release: drain vmem + wbL2 so h is at the coherent point
    int old = __hip_atomic_fetch_add(&bar[0], 1, __ATOMIC_RELAXED,
                                     __HIP_MEMORY_SCOPE_AGENT);
    if (old == gen * NBLK - 1) {
      __hip_atomic_store(&bar[1], gen, __ATOMIC_RELEASE,
                         __HIP_MEMORY_SCOPE_AGENT);
    } else {
      while (__hip_atomic_load(&bar[1], __ATOMIC_RELAXED,
                               __HIP_MEMORY_SCOPE_AGENT) < gen)
        __builtin_amdgcn_s_sleep(1);
    }
    __threadfence();  // acquire: invalidate L1/L2 so fresh h is visible
  }
  __syncthreads();
}

// ---------------------------------------------------------------------------
// Prep: transpose+cast one fp32 [1024(k)][1024(n)] matrix -> bf16 [n][k]
// ---------------------------------------------------------------------------
__global__ __launch_bounds__(256) void k_transpose_cast(
    const float* __restrict__ src, unsigned short* __restrict__ dst) {
  __shared__ float tile[32][33];
  const int bx = blockIdx.x;
  const int n0 = (bx & 31) * 32, k0 = (bx >> 5) * 32;
  const int tx = threadIdx.x & 31, ty = threadIdx.x >> 5;
#pragma unroll
  for (int i = 0; i < 4; ++i)
    tile[ty + i * 8][tx] = src[(size_t)(k0 + ty + i * 8) * 1024 + n0 + tx];
  __syncthreads();
#pragma unroll
  for (int i = 0; i < 4; ++i)
    dst[(size_t)(n0 + ty + i * 8) * 1024 + k0 + tx] = f2bf(tile[tx][ty + i * 8]);
}

// ---------------------------------------------------------------------------
// Prep: cast x fp32 -> bf16 (vectorized 8/thread); also zero the barrier
// ---------------------------------------------------------------------------
__global__ __launch_bounds__(256) void k_cast_x(
    const float* __restrict__ src, unsigned short* __restrict__ dst, int n8,
    int* __restrict__ bar) {
  if (blockIdx.x == 0 && threadIdx.x < 2)
    __hip_atomic_store(&bar[threadIdx.x], 0, __ATOMIC_RELAXED,
                       __HIP_MEMORY_SCOPE_AGENT);
  int idx = blockIdx.x * 256 + threadIdx.x;
  if (idx >= n8) return;
  const floatx4* s = (const floatx4*)(src + (size_t)idx * 8);
  floatx4 a = s[0], b = s[1];
  short8 o;
  o[0] = (short)f2bf(a[0]); o[1] = (short)f2bf(a[1]);
  o[2] = (short)f2bf(a[2]); o[3] = (short)f2bf(a[3]);
  o[4] = (short)f2bf(b[0]); o[5] = (short)f2bf(b[1]);
  o[6] = (short)f2bf(b[2]); o[7] = (short)f2bf(b[3]);
  *(short8*)(dst + (size_t)idx * 8) = o;
}

// ---------------------------------------------------------------------------
// Phase 1 GEMM: gates[(s*64+b)][n] = x[b*512+s][k] * Wt[n][k]^T  (s-major out)
// ---------------------------------------------------------------------------
__global__ __launch_bounds__(256) void k_gemm_xw(
    const unsigned short* __restrict__ A,   // [32768][1024]
    const unsigned short* __restrict__ Bt,  // [4096][1024]
    unsigned short* __restrict__ C)         // [512 s][64 b][4096]
{
  __shared__ unsigned short As[128 * 32];
  __shared__ unsigned short Bs[128 * 32];
  const int bid = blockIdx.x;
  const int bm = bid & 255;
  const int bn = bid >> 8;
  const int m0 = bm * 128, n0 = bn * 128;
  const int tid = threadIdx.x;
  const int lane = tid & 63, wid = tid >> 6;

  const unsigned short* ga = A  + (size_t)(m0 + (tid >> 2)) * 1024 + (tid & 3) * 8;
  const unsigned short* gb = Bt + (size_t)(n0 + (tid >> 2)) * 1024 + (tid & 3) * 8;
  unsigned short* lA = As + wid * 512;
  unsigned short* lB = Bs + wid * 512;

  floatx4 acc[4][4] = {};
  const int wm = (wid >> 1) * 64, wn = (wid & 1) * 64;
  const int lr = lane & 15, lk = (lane >> 4) * 8;

  for (int k0 = 0; k0 < 1024; k0 += 32) {
    gload_lds16(ga + k0, lA);
    gload_lds16(ga + 64 * 1024 + k0, lA + 2048);
    gload_lds16(gb + k0, lB);
    gload_lds16(gb + 64 * 1024 + k0, lB + 2048);
    __syncthreads();
    short8 af[4], bfv[4];
#pragma unroll
    for (int mt = 0; mt < 4; ++mt)
      af[mt] = *(const short8*)(As + (wm + mt * 16 + lr) * 32 + lk);
#pragma unroll
    for (int nt = 0; nt < 4; ++nt)
      bfv[nt] = *(const short8*)(Bs + (wn + nt * 16 + lr) * 32 + lk);
#pragma unroll
    for (int mt = 0; mt < 4; ++mt)
#pragma unroll
      for (int nt = 0; nt < 4; ++nt)
        acc[mt][nt] = __builtin_amdgcn_mfma_f32_16x16x32_bf16(
            af[mt], bfv[nt], acc[mt][nt], 0, 0, 0);
    __syncthreads();
  }

  // epilogue: permute rows m=b*512+s -> out row s*64+b (s-major gates)
#pragma unroll
  for (int mt = 0; mt < 4; ++mt) {
    const int row = m0 + wm + mt * 16 + (lane >> 4) * 4;
#pragma unroll
    for (int r = 0; r < 4; ++r) {
      const int rr = row + r;
      unsigned short* cp = C + (size_t)((rr & 511) * 64 + (rr >> 9)) * 4096;
#pragma unroll
      for (int nt = 0; nt < 4; ++nt) {
        const int col = n0 + wn + nt * 16 + lr;
        cp[col] = f2bf(acc[mt][nt][r]);
      }
    }
  }
}

// ---------------------------------------------------------------------------
// Phase 2: recurrence. 64 persistent blocks x 512 threads (cooperative).
// Block owns 16 h-cols (=> 64 gate cols: 4 gates x 16). U frags in VGPRs.
// 8 waves split K=1024 into 8x128; cross-wave reduce via ds_add_f32.
// Hand-rolled grid barrier once per step.
// ---------------------------------------------------------------------------
__global__ __launch_bounds__(512, 2) void k_recur64(
    const unsigned short* __restrict__ gates,  // [512 s][64 b][4096] bf16
    const unsigned short* __restrict__ Ut,     // [4][1024 n][1024 k] bf16
    const float* __restrict__ bF, const float* __restrict__ bI,
    const float* __restrict__ bO, const float* __restrict__ bC,
    unsigned short* __restrict__ hbuf,         // [2][64][1024] bf16
    int* __restrict__ bar,
    float* __restrict__ out)                   // ys | h | c
{
  __shared__ float part1[64][69];              // [gatecol_loc][batch], odd pad
  const int bid = blockIdx.x;                  // 0..63
  const int tid = threadIdx.x;                 // 0..511
  const int lane = tid & 63, w = tid >> 6;
  const int lr = lane & 15, lk = (lane >> 4) * 8;
  const int hcol0 = bid * 16;

  // Preload U fragments: wave w owns K-slice [w*128, w*128+128)
  short8 bfrag[4][4];                          // [gate n][kt]
#pragma unroll
  for (int n = 0; n < 4; ++n) {
    const unsigned short* up = Ut + ((size_t)n << 20) +
                               (size_t)(hcol0 + lr) * 1024 + w * 128 + lk;
#pragma unroll
    for (int kt = 0; kt < 4; ++kt)
      bfrag[n][kt] = *(const short8*)(up + kt * 32);
  }

  // Elementwise identity: thread -> (batch eb, col pair 2*ej, 2*ej+1)
  const int eb = tid >> 3, ej = tid & 7;
  const int hc0 = 2 * ej;                      // local col (even)
  const int gc = hcol0 + hc0;                  // global h col (even)
  float2 bias[4];
  bias[0] = *(const float2*)(bF + gc);
  bias[1] = *(const float2*)(bI + gc);
  bias[2] = *(const float2*)(bO + gc);
  bias[3] = *(const float2*)(bC + gc);

  // zero LDS accumulator + own slice of h_{-1} (buf 0)
  for (int i = tid; i < 64 * 69; i += 512) ((float*)part1)[i] = 0.0f;
  *(unsigned int*)(hbuf + eb * 1024 + gc) = 0u;

  float c0 = 0.f, c1 = 0.f, h0v = 0.f, h1v = 0.f;
  int gen = 1;
  grid_barrier(bar, gen++);

  // prefetch gates for s=0
  unsigned int g_nxt[4];
#pragma unroll
  for (int g = 0; g < 4; ++g)
    g_nxt[g] = *(const unsigned int*)(gates + (size_t)eb * 4096 + g * 1024 + gc);

  for (int s = 0; s < SS; ++s) {
    const unsigned short* hp = hbuf + (s & 1) * 65536;
    unsigned short* hw = hbuf + ((s & 1) ^ 1) * 65536;
    unsigned int gcur[4] = { g_nxt[0], g_nxt[1], g_nxt[2], g_nxt[3] };

    // ---- MFMA over this wave's K-slice, double-buffered A loads ----
    floatx4 acc[4][4] = {};                    // [mt][gate n]
    const unsigned short* hbase = hp + w * 128 + lk;
    short8 a0[4], a1[4];
#pragma unroll
    for (int mt = 0; mt < 4; ++mt)
      a0[mt] = *(const short8*)(hbase + (size_t)(mt * 16 + lr) * 1024);
#pragma unroll
    for (int kt = 0; kt < 4; ++kt) {
      const short8* cur = (kt & 1) ? a1 : a0;
      short8* nxt = (kt & 1) ? a0 : a1;
      if (kt < 3) {
#pragma unroll
        for (int mt = 0; mt < 4; ++mt)
          nxt[mt] = *(const short8*)(hbase + (kt + 1) * 32 +
                                     (size_t)(mt * 16 + lr) * 1024);
      }
#pragma unroll
      for (int mt = 0; mt < 4; ++mt)
#pragma unroll
        for (int n = 0; n < 4; ++n)
          acc[mt][n] = __builtin_amdgcn_mfma_f32_16x16x32_bf16(
              cur[mt], bfrag[n][kt], acc[mt][n], 0, 0, 0);
    }

    // ---- cross-wave reduce: ds_add_f32 into part1 ----
    const int r0 = (lane >> 4) * 4;
#pragma unroll
    for (int mt = 0; mt < 4; ++mt)
#pragma unroll
      for (int n = 0; n < 4; ++n) {
        float* p = &part1[n * 16 + lr][mt * 16 + r0];
#pragma unroll
        for (int r = 0; r < 4; ++r) atomicAdd(p + r, acc[mt][n][r]);
      }

    // prefetch next step's gates (ride through the barrier in regs)
    const int sn = (s + 1 < SS) ? s + 1 : s;
#pragma unroll
    for (int g = 0; g < 4; ++g)
      g_nxt[g] = *(const unsigned int*)(gates + ((size_t)sn * 64 + eb) * 4096 +
                                        g * 1024 + gc);

    __syncthreads();  // all ds_adds visible

    // ---- gates + elementwise for 2 (b, col) pairs ----
    float pre0[4], pre1[4];
#pragma unroll
    for (int g = 0; g < 4; ++g) {
      pre0[g] = part1[g * 16 + hc0][eb] +
                bf2f((unsigned short)(gcur[g] & 0xffffu)) + bias[g].x;
      pre1[g] = part1[g * 16 + hc0 + 1][eb] +
                bf2f((unsigned short)(gcur[g] >> 16)) + bias[g].y;
    }
    float f0 = sigmoidf_(pre0[0]), f1 = sigmoidf_(pre1[0]);
    float i0 = sigmoidf_(pre0[1]), i1 = sigmoidf_(pre1[1]);
    float o0 = sigmoidf_(pre0[2]), o1 = sigmoidf_(pre1[2]);
    float q0 = tanhf_(pre0[3]),    q1 = tanhf_(pre1[3]);
    c0 = f0 * c0 + i0 * q0;  c1 = f1 * c1 + i1 * q1;
    h0v = o0 * tanhf_(c0);   h1v = o1 * tanhf_(c1);

    __syncthreads();  // reads of part1 done before re-zero
    for (int i = tid; i < 64 * 69; i += 512) ((float*)part1)[i] = 0.0f;

    // store h (bf16 pair) + ys (fp32 pair, nontemporal)
    unsigned int hpack = (unsigned int)f2bf(h0v) |
                         ((unsigned int)f2bf(h1v) << 16);
    *(unsigned int*)(hw + eb * 1024 + gc) = hpack;
    float2 yv; yv.x = h0v; yv.y = h1v;
    __builtin_nontemporal_store(
        *(double*)&yv, (double*)(out + ((size_t)eb * 512 + s) * 1024 + gc));

    grid_barrier(bar, gen++);
  }

  // final (h, c)
  const size_t ys_sz = (size_t)BB * SS * HH;
  out[ys_sz + (size_t)eb * 1024 + gc]             = h0v;
  out[ys_sz + (size_t)eb * 1024 + gc + 1]         = h1v;
  out[ys_sz + 65536 + (size_t)eb * 1024 + gc]     = c0;
  out[ys_sz + 65536 + (size_t)eb * 1024 + gc + 1] = c1;
}

// ---------------------------------------------------------------------------
// Host launcher
// ---------------------------------------------------------------------------
extern "C" void kernel_launch(void* const* d_in, const int* in_sizes, int n_in,
                              void* d_out, int out_size, void* d_ws, size_t ws_size,
                              hipStream_t stream) {
  const float* x = (const float*)d_in[0];
  const float* w[4] = { (const float*)d_in[1], (const float*)d_in[4],
                        (const float*)d_in[7], (const float*)d_in[10] };
  const float* u[4] = { (const float*)d_in[2], (const float*)d_in[5],
                        (const float*)d_in[8], (const float*)d_in[11] };
  const float* b[4] = { (const float*)d_in[3], (const float*)d_in[6],
                        (const float*)d_in[9], (const float*)d_in[12] };

  const size_t OFF_WT = 0;                          //  8 MB  Wt bf16
  const size_t OFF_UT = 8u << 20;                   //  8 MB  Ut bf16
  const size_t OFF_XB = 16u << 20;                  // 64 MB  x  bf16
  const size_t OFF_GX = 80u << 20;                  // 256 MB gates bf16
  const size_t OFF_HB = (80u << 20) + (256u << 20); // 256 KB h dbuf
  const size_t OFF_BAR = OFF_HB + 2 * 65536 * 2;    // barrier ints
  const size_t NEED = OFF_BAR + 256;
  if (ws_size < NEED) return;

  char* ws = (char*)d_ws;
  unsigned short* Wt = (unsigned short*)(ws + OFF_WT);
  unsigned short* Ut = (unsigned short*)(ws + OFF_UT);
  unsigned short* Xb = (unsigned short*)(ws + OFF_XB);
  unsigned short* Gx = (unsigned short*)(ws + OFF_GX);
  unsigned short* Hb = (unsigned short*)(ws + OFF_HB);
  int* Bar = (int*)(ws + OFF_BAR);

  for (int gi = 0; gi < 4; ++gi) {
    k_transpose_cast<<<1024, 256, 0, stream>>>(w[gi], Wt + (size_t)gi * 1024 * 1024);
    k_transpose_cast<<<1024, 256, 0, stream>>>(u[gi], Ut + (size_t)gi * 1024 * 1024);
  }
  k_cast_x<<<(MM * II / 8) / 256, 256, 0, stream>>>(x, Xb, MM * II / 8, Bar);
  k_gemm_xw<<<256 * 32, 256, 0, stream>>>(Xb, Wt, Gx);

  const unsigned short* gx_p = Gx;
  const unsigned short* ut_p = Ut;
  const float* b0 = b[0]; const float* b1 = b[1];
  const float* b2 = b[2]; const float* b3 = b[3];
  unsigned short* hb_p = Hb;
  int* bar_p = Bar;
  float* out_p = (float*)d_out;
  void* args[] = { (void*)&gx_p, (void*)&ut_p, (void*)&b0, (void*)&b1,
                   (void*)&b2, (void*)&b3, (void*)&hb_p, (void*)&bar_p,
                   (void*)&out_p };
  hipLaunchCooperativeKernel(k_recur64, dim3(NBLK), dim3(512), args, 0, stream);
}

// Round 3
// 25314.223 us; speedup vs baseline: 1.0452x; 1.0452x over previous
//
#include <hip/hip_runtime.h>
#include <stdint.h>

typedef __attribute__((ext_vector_type(8))) short short8;
typedef __attribute__((ext_vector_type(4))) float floatx4;

#define DI __device__ __forceinline__

// Problem dims
constexpr int BB = 64;          // batch
constexpr int SS = 512;         // seq len
constexpr int II = 1024;        // input size
constexpr int HH = 1024;        // hidden size
constexpr int MM = BB * SS;     // 32768 GEMM rows
constexpr int NBLK = 64;        // recurrence blocks

DI unsigned short f2bf(float f) {
  union { float f; unsigned int u; } v; v.f = f;
  unsigned int u = v.u;
  return (unsigned short)((u + 0x7FFFu + ((u >> 16) & 1u)) >> 16);  // RNE
}
DI float bf2f(unsigned short u) {
  union { unsigned int u; float f; } v; v.u = ((unsigned int)u) << 16;
  return v.f;
}
DI float sigmoidf_(float x) { return 1.0f / (1.0f + __expf(-x)); }
DI float tanhf_(float x)    { return 2.0f / (1.0f + __expf(-2.0f * x)) - 1.0f; }

DI void gload_lds16(const unsigned short* g, unsigned short* l) {
  typedef __attribute__((address_space(1))) const void gv_t;
  typedef __attribute__((address_space(3))) void lv_t;
  __builtin_amdgcn_global_load_lds((gv_t*)(uintptr_t)g, (lv_t*)(uintptr_t)l, 16, 0, 0);
}

// L2-bypassing (coherent-point) accessors. Relaxed agent-scope atomics emit
// NO buffer_wbl2 / buffer_inv — they simply execute at L3. This is the whole
// point of R3: zero cache-maintenance ops in the steady-state loop.
DI short8 load_h16(const unsigned short* p) {
  union { unsigned long long q[2]; short8 v; } u;
  u.q[0] = __hip_atomic_load((const unsigned long long*)p,
                             __ATOMIC_RELAXED, __HIP_MEMORY_SCOPE_AGENT);
  u.q[1] = __hip_atomic_load((const unsigned long long*)(p + 4),
                             __ATOMIC_RELAXED, __HIP_MEMORY_SCOPE_AGENT);
  return u.v;
}
DI void store_h4(unsigned short* p, unsigned int v) {
  __hip_atomic_store((unsigned int*)p, v, __ATOMIC_RELAXED,
                     __HIP_MEMORY_SCOPE_AGENT);
}

// Fence-free grid barrier. bar[0] = arrive count (line 0), bar[16] = release
// generation (line 1, separate 64B cacheline). Ordering argument:
//  - __syncthreads() drains vmcnt(0) per wave => every h atomic-store has
//    COMPLETED at L3 before thread0 issues the arrive RMW.
//  - a spinner observes gen only causally after all arrives; its subsequent
//    h atomic-loads are issued after the closing __syncthreads() and read L3
//    directly => they see all blocks' completed h stores. No fences needed.
DI void grid_barrier(int* bar, int gen) {
  __syncthreads();
  if (threadIdx.x == 0) {
    int old = __hip_atomic_fetch_add(&bar[0], 1, __ATOMIC_RELAXED,
                                     __HIP_MEMORY_SCOPE_AGENT);
    if (old == gen * NBLK - 1) {
      __hip_atomic_store(&bar[16], gen, __ATOMIC_RELAXED,
                         __HIP_MEMORY_SCOPE_AGENT);
    } else {
      while (__hip_atomic_load(&bar[16], __ATOMIC_RELAXED,
                               __HIP_MEMORY_SCOPE_AGENT) < gen)
        __builtin_amdgcn_s_sleep(4);
    }
  }
  __syncthreads();
}

// ---------------------------------------------------------------------------
// Prep: transpose+cast one fp32 [1024(k)][1024(n)] matrix -> bf16 [n][k]
// ---------------------------------------------------------------------------
__global__ __launch_bounds__(256) void k_transpose_cast(
    const float* __restrict__ src, unsigned short* __restrict__ dst) {
  __shared__ float tile[32][33];
  const int bx = blockIdx.x;
  const int n0 = (bx & 31) * 32, k0 = (bx >> 5) * 32;
  const int tx = threadIdx.x & 31, ty = threadIdx.x >> 5;
#pragma unroll
  for (int i = 0; i < 4; ++i)
    tile[ty + i * 8][tx] = src[(size_t)(k0 + ty + i * 8) * 1024 + n0 + tx];
  __syncthreads();
#pragma unroll
  for (int i = 0; i < 4; ++i)
    dst[(size_t)(n0 + ty + i * 8) * 1024 + k0 + tx] = f2bf(tile[tx][ty + i * 8]);
}

// ---------------------------------------------------------------------------
// Prep: cast x fp32 -> bf16 (vectorized 8/thread); also zero the barrier
// ---------------------------------------------------------------------------
__global__ __launch_bounds__(256) void k_cast_x(
    const float* __restrict__ src, unsigned short* __restrict__ dst, int n8,
    int* __restrict__ bar) {
  if (blockIdx.x == 0 && threadIdx.x < 32)
    __hip_atomic_store(&bar[threadIdx.x], 0, __ATOMIC_RELAXED,
                       __HIP_MEMORY_SCOPE_AGENT);
  int idx = blockIdx.x * 256 + threadIdx.x;
  if (idx >= n8) return;
  const floatx4* s = (const floatx4*)(src + (size_t)idx * 8);
  floatx4 a = s[0], b = s[1];
  short8 o;
  o[0] = (short)f2bf(a[0]); o[1] = (short)f2bf(a[1]);
  o[2] = (short)f2bf(a[2]); o[3] = (short)f2bf(a[3]);
  o[4] = (short)f2bf(b[0]); o[5] = (short)f2bf(b[1]);
  o[6] = (short)f2bf(b[2]); o[7] = (short)f2bf(b[3]);
  *(short8*)(dst + (size_t)idx * 8) = o;
}

// ---------------------------------------------------------------------------
// Phase 1 GEMM: gates[(s*64+b)][n] = x[b*512+s][k] * Wt[n][k]^T  (s-major out)
// ---------------------------------------------------------------------------
__global__ __launch_bounds__(256) void k_gemm_xw(
    const unsigned short* __restrict__ A,   // [32768][1024]
    const unsigned short* __restrict__ Bt,  // [4096][1024]
    unsigned short* __restrict__ C)         // [512 s][64 b][4096]
{
  __shared__ unsigned short As[128 * 32];
  __shared__ unsigned short Bs[128 * 32];
  const int bid = blockIdx.x;
  const int bm = bid & 255;
  const int bn = bid >> 8;
  const int m0 = bm * 128, n0 = bn * 128;
  const int tid = threadIdx.x;
  const int lane = tid & 63, wid = tid >> 6;

  const unsigned short* ga = A  + (size_t)(m0 + (tid >> 2)) * 1024 + (tid & 3) * 8;
  const unsigned short* gb = Bt + (size_t)(n0 + (tid >> 2)) * 1024 + (tid & 3) * 8;
  unsigned short* lA = As + wid * 512;
  unsigned short* lB = Bs + wid * 512;

  floatx4 acc[4][4] = {};
  const int wm = (wid >> 1) * 64, wn = (wid & 1) * 64;
  const int lr = lane & 15, lk = (lane >> 4) * 8;

  for (int k0 = 0; k0 < 1024; k0 += 32) {
    gload_lds16(ga + k0, lA);
    gload_lds16(ga + 64 * 1024 + k0, lA + 2048);
    gload_lds16(gb + k0, lB);
    gload_lds16(gb + 64 * 1024 + k0, lB + 2048);
    __syncthreads();
    short8 af[4], bfv[4];
#pragma unroll
    for (int mt = 0; mt < 4; ++mt)
      af[mt] = *(const short8*)(As + (wm + mt * 16 + lr) * 32 + lk);
#pragma unroll
    for (int nt = 0; nt < 4; ++nt)
      bfv[nt] = *(const short8*)(Bs + (wn + nt * 16 + lr) * 32 + lk);
#pragma unroll
    for (int mt = 0; mt < 4; ++mt)
#pragma unroll
      for (int nt = 0; nt < 4; ++nt)
        acc[mt][nt] = __builtin_amdgcn_mfma_f32_16x16x32_bf16(
            af[mt], bfv[nt], acc[mt][nt], 0, 0, 0);
    __syncthreads();
  }

  // epilogue: permute rows m=b*512+s -> out row s*64+b (s-major gates)
#pragma unroll
  for (int mt = 0; mt < 4; ++mt) {
    const int row = m0 + wm + mt * 16 + (lane >> 4) * 4;
#pragma unroll
    for (int r = 0; r < 4; ++r) {
      const int rr = row + r;
      unsigned short* cp = C + (size_t)((rr & 511) * 64 + (rr >> 9)) * 4096;
#pragma unroll
      for (int nt = 0; nt < 4; ++nt) {
        const int col = n0 + wn + nt * 16 + lr;
        cp[col] = f2bf(acc[mt][nt][r]);
      }
    }
  }
}

// ---------------------------------------------------------------------------
// Phase 2: recurrence. 64 persistent blocks x 512 threads (cooperative).
// Identical geometry/reduce to R2; only the coherence protocol changed:
// h via relaxed agent atomics (L2-bypass), barrier fence-free.
// ---------------------------------------------------------------------------
__global__ __launch_bounds__(512, 2) void k_recur64(
    const unsigned short* __restrict__ gates,  // [512 s][64 b][4096] bf16
    const unsigned short* __restrict__ Ut,     // [4][1024 n][1024 k] bf16
    const float* __restrict__ bF, const float* __restrict__ bI,
    const float* __restrict__ bO, const float* __restrict__ bC,
    unsigned short* __restrict__ hbuf,         // [2][64][1024] bf16
    int* __restrict__ bar,
    float* __restrict__ out)                   // ys | h | c
{
  __shared__ float part1[64][69];              // [gatecol_loc][batch], odd pad
  const int bid = blockIdx.x;                  // 0..63
  const int tid = threadIdx.x;                 // 0..511
  const int lane = tid & 63, w = tid >> 6;
  const int lr = lane & 15, lk = (lane >> 4) * 8;
  const int hcol0 = bid * 16;

  // Preload U fragments: wave w owns K-slice [w*128, w*128+128)
  short8 bfrag[4][4];                          // [gate n][kt]
#pragma unroll
  for (int n = 0; n < 4; ++n) {
    const unsigned short* up = Ut + ((size_t)n << 20) +
                               (size_t)(hcol0 + lr) * 1024 + w * 128 + lk;
#pragma unroll
    for (int kt = 0; kt < 4; ++kt)
      bfrag[n][kt] = *(const short8*)(up + kt * 32);
  }

  // Elementwise identity: thread -> (batch eb, col pair 2*ej, 2*ej+1)
  const int eb = tid >> 3, ej = tid & 7;
  const int hc0 = 2 * ej;                      // local col (even)
  const int gc = hcol0 + hc0;                  // global h col (even)
  float2 bias[4];
  bias[0] = *(const float2*)(bF + gc);
  bias[1] = *(const float2*)(bI + gc);
  bias[2] = *(const float2*)(bO + gc);
  bias[3] = *(const float2*)(bC + gc);

  // zero LDS accumulator + own slice of h_{-1} (buf 0)
  for (int i = tid; i < 64 * 69; i += 512) ((float*)part1)[i] = 0.0f;
  store_h4(hbuf + eb * 1024 + gc, 0u);

  float c0 = 0.f, c1 = 0.f, h0v = 0.f, h1v = 0.f;
  int gen = 1;
  grid_barrier(bar, gen++);

  // prefetch gates for s=0 (plain cached loads; L2 never invalidated now)
  unsigned int g_nxt[4];
#pragma unroll
  for (int g = 0; g < 4; ++g)
    g_nxt[g] = *(const unsigned int*)(gates + (size_t)eb * 4096 + g * 1024 + gc);

  for (int s = 0; s < SS; ++s) {
    const unsigned short* hp = hbuf + (s & 1) * 65536;
    unsigned short* hw = hbuf + ((s & 1) ^ 1) * 65536;
    unsigned int gcur[4] = { g_nxt[0], g_nxt[1], g_nxt[2], g_nxt[3] };

    // ---- MFMA over this wave's K-slice; A from L3 via relaxed atomics ----
    floatx4 acc[4][4] = {};                    // [mt][gate n]
    const unsigned short* hbase = hp + w * 128 + lk;
    short8 a0[4], a1[4];
#pragma unroll
    for (int mt = 0; mt < 4; ++mt)
      a0[mt] = load_h16(hbase + (size_t)(mt * 16 + lr) * 1024);
#pragma unroll
    for (int kt = 0; kt < 4; ++kt) {
      const short8* cur = (kt & 1) ? a1 : a0;
      short8* nxt = (kt & 1) ? a0 : a1;
      if (kt < 3) {
#pragma unroll
        for (int mt = 0; mt < 4; ++mt)
          nxt[mt] = load_h16(hbase + (kt + 1) * 32 +
                             (size_t)(mt * 16 + lr) * 1024);
      }
#pragma unroll
      for (int mt = 0; mt < 4; ++mt)
#pragma unroll
        for (int n = 0; n < 4; ++n)
          acc[mt][n] = __builtin_amdgcn_mfma_f32_16x16x32_bf16(
              cur[mt], bfrag[n][kt], acc[mt][n], 0, 0, 0);
    }

    // ---- cross-wave reduce: ds_add_f32 into part1 ----
    const int r0 = (lane >> 4) * 4;
#pragma unroll
    for (int mt = 0; mt < 4; ++mt)
#pragma unroll
      for (int n = 0; n < 4; ++n) {
        float* p = &part1[n * 16 + lr][mt * 16 + r0];
#pragma unroll
        for (int r = 0; r < 4; ++r) atomicAdd(p + r, acc[mt][n][r]);
      }

    // prefetch next step's gates (ride through the barrier in regs)
    const int sn = (s + 1 < SS) ? s + 1 : s;
#pragma unroll
    for (int g = 0; g < 4; ++g)
      g_nxt[g] = *(const unsigned int*)(gates + ((size_t)sn * 64 + eb) * 4096 +
                                        g * 1024 + gc);

    __syncthreads();  // all ds_adds visible

    // ---- gates + elementwise for 2 (b, col) pairs ----
    float pre0[4], pre1[4];
#pragma unroll
    for (int g = 0; g < 4; ++g) {
      pre0[g] = part1[g * 16 + hc0][eb] +
                bf2f((unsigned short)(gcur[g] & 0xffffu)) + bias[g].x;
      pre1[g] = part1[g * 16 + hc0 + 1][eb] +
                bf2f((unsigned short)(gcur[g] >> 16)) + bias[g].y;
    }
    float f0 = sigmoidf_(pre0[0]), f1 = sigmoidf_(pre1[0]);
    float i0 = sigmoidf_(pre0[1]), i1 = sigmoidf_(pre1[1]);
    float o0 = sigmoidf_(pre0[2]), o1 = sigmoidf_(pre1[2]);
    float q0 = tanhf_(pre0[3]),    q1 = tanhf_(pre1[3]);
    c0 = f0 * c0 + i0 * q0;  c1 = f1 * c1 + i1 * q1;
    h0v = o0 * tanhf_(c0);   h1v = o1 * tanhf_(c1);

    __syncthreads();  // reads of part1 done before re-zero
    for (int i = tid; i < 64 * 69; i += 512) ((float*)part1)[i] = 0.0f;

    // store h (bf16 pair, L2-bypass) + ys (fp32 pair, plain nontemporal)
    unsigned int hpack = (unsigned int)f2bf(h0v) |
                         ((unsigned int)f2bf(h1v) << 16);
    store_h4(hw + eb * 1024 + gc, hpack);
    float2 yv; yv.x = h0v; yv.y = h1v;
    __builtin_nontemporal_store(
        *(double*)&yv, (double*)(out + ((size_t)eb * 512 + s) * 1024 + gc));

    grid_barrier(bar, gen++);
  }

  // final (h, c)
  const size_t ys_sz = (size_t)BB * SS * HH;
  out[ys_sz + (size_t)eb * 1024 + gc]             = h0v;
  out[ys_sz + (size_t)eb * 1024 + gc + 1]         = h1v;
  out[ys_sz + 65536 + (size_t)eb * 1024 + gc]     = c0;
  out[ys_sz + 65536 + (size_t)eb * 1024 + gc + 1] = c1;
}

// ---------------------------------------------------------------------------
// Host launcher
// ---------------------------------------------------------------------------
extern "C" void kernel_launch(void* const* d_in, const int* in_sizes, int n_in,
                              void* d_out, int out_size, void* d_ws, size_t ws_size,
                              hipStream_t stream) {
  const float* x = (const float*)d_in[0];
  const float* w[4] = { (const float*)d_in[1], (const float*)d_in[4],
                        (const float*)d_in[7], (const float*)d_in[10] };
  const float* u[4] = { (const float*)d_in[2], (const float*)d_in[5],
                        (const float*)d_in[8], (const float*)d_in[11] };
  const float* b[4] = { (const float*)d_in[3], (const float*)d_in[6],
                        (const float*)d_in[9], (const float*)d_in[12] };

  const size_t OFF_WT = 0;                          //  8 MB  Wt bf16
  const size_t OFF_UT = 8u << 20;                   //  8 MB  Ut bf16
  const size_t OFF_XB = 16u << 20;                  // 64 MB  x  bf16
  const size_t OFF_GX = 80u << 20;                  // 256 MB gates bf16
  const size_t OFF_HB = (80u << 20) + (256u << 20); // 256 KB h dbuf
  const size_t OFF_BAR = OFF_HB + 2 * 65536 * 2;    // barrier ints
  const size_t NEED = OFF_BAR + 256;
  if (ws_size < NEED) return;

  char* ws = (char*)d_ws;
  unsigned short* Wt = (unsigned short*)(ws + OFF_WT);
  unsigned short* Ut = (unsigned short*)(ws + OFF_UT);
  unsigned short* Xb = (unsigned short*)(ws + OFF_XB);
  unsigned short* Gx = (unsigned short*)(ws + OFF_GX);
  unsigned short* Hb = (unsigned short*)(ws + OFF_HB);
  int* Bar = (int*)(ws + OFF_BAR);

  for (int gi = 0; gi < 4; ++gi) {
    k_transpose_cast<<<1024, 256, 0, stream>>>(w[gi], Wt + (size_t)gi * 1024 * 1024);
    k_transpose_cast<<<1024, 256, 0, stream>>>(u[gi], Ut + (size_t)gi * 1024 * 1024);
  }
  k_cast_x<<<(MM * II / 8) / 256, 256, 0, stream>>>(x, Xb, MM * II / 8, Bar);
  k_gemm_xw<<<256 * 32, 256, 0, stream>>>(Xb, Wt, Gx);

  const unsigned short* gx_p = Gx;
  const unsigned short* ut_p = Ut;
  const float* b0 = b[0]; const float* b1 = b[1];
  const float* b2 = b[2]; const float* b3 = b[3];
  unsigned short* hb_p = Hb;
  int* bar_p = Bar;
  float* out_p = (float*)d_out;
  void* args[] = { (void*)&gx_p, (void*)&ut_p, (void*)&b0, (void*)&b1,
                   (void*)&b2, (void*)&b3, (void*)&hb_p, (void*)&bar_p,
                   (void*)&out_p };
  hipLaunchCooperativeKernel(k_recur64, dim3(NBLK), dim3(512), args, 0, stream);
}

// Round 4
// 24876.297 us; speedup vs baseline: 1.0636x; 1.0176x over previous
//
#include <hip/hip_runtime.h>
#include <stdint.h>

typedef __attribute__((ext_vector_type(8))) short short8;
typedef __attribute__((ext_vector_type(4))) float floatx4;

#define DI __device__ __forceinline__

// Problem dims
constexpr int BB = 64;          // batch
constexpr int SS = 512;         // seq len
constexpr int II = 1024;        // input size
constexpr int HH = 1024;        // hidden size
constexpr int MM = BB * SS;     // 32768 GEMM rows
constexpr int NBLK = 64;        // recurrence blocks

DI unsigned short f2bf(float f) {
  union { float f; unsigned int u; } v; v.f = f;
  unsigned int u = v.u;
  return (unsigned short)((u + 0x7FFFu + ((u >> 16) & 1u)) >> 16);  // RNE
}
DI float bf2f(unsigned short u) {
  union { unsigned int u; float f; } v; v.u = ((unsigned int)u) << 16;
  return v.f;
}
DI float sigmoidf_(float x) { return 1.0f / (1.0f + __expf(-x)); }
DI float tanhf_(float x)    { return 2.0f / (1.0f + __expf(-2.0f * x)) - 1.0f; }

DI void gload_lds16(const unsigned short* g, unsigned short* l) {
  typedef __attribute__((address_space(1))) const void gv_t;
  typedef __attribute__((address_space(3))) void lv_t;
  __builtin_amdgcn_global_load_lds((gv_t*)(uintptr_t)g, (lv_t*)(uintptr_t)l, 16, 0, 0);
}

// L2-bypassing (coherent-point) accessors — no cache-maintenance ops.
DI short8 load_h16(const unsigned short* p) {
  union { unsigned long long q[2]; short8 v; } u;
  u.q[0] = __hip_atomic_load((const unsigned long long*)p,
                             __ATOMIC_RELAXED, __HIP_MEMORY_SCOPE_AGENT);
  u.q[1] = __hip_atomic_load((const unsigned long long*)(p + 4),
                             __ATOMIC_RELAXED, __HIP_MEMORY_SCOPE_AGENT);
  return u.v;
}
DI void store_h4(unsigned short* p, unsigned int v) {
  __hip_atomic_store((unsigned int*)p, v, __ATOMIC_RELAXED,
                     __HIP_MEMORY_SCOPE_AGENT);
}

// Distributed-flag grid barrier: ZERO same-address RMWs, zero fences.
// Block i owns flags[i*64] (256 B apart -> distinct cachelines/slices,
// single writer). Wave 0 gathers all 64 flags, one per lane; the exec-mask
// loop retires lanes as their flag reaches gen.
// Ordering: the compiler emits s_waitcnt vmcnt(0) before s_barrier, so every
// wave's h atomic-stores are COMPLETE at L3 before the flag store is issued;
// a block passes the poll only after observing all 64 flags >= gen, hence
// after all blocks' h stores completed at L3. Its subsequent h atomic-loads
// read L3 directly.
DI void grid_barrier(int* flags, int gen) {
  __syncthreads();                 // all waves' stores drained (vmcnt 0)
  const int t = threadIdx.x;
  if (t < 64) {
    if (t == (int)blockIdx.x)
      __hip_atomic_store(&flags[t * 64], gen, __ATOMIC_RELAXED,
                         __HIP_MEMORY_SCOPE_AGENT);
    while (__hip_atomic_load(&flags[t * 64], __ATOMIC_RELAXED,
                             __HIP_MEMORY_SCOPE_AGENT) < gen) {
    }
  }
  __syncthreads();
}

// ---------------------------------------------------------------------------
// Prep: transpose+cast one fp32 [1024(k)][1024(n)] matrix -> bf16 [n][k]
// ---------------------------------------------------------------------------
__global__ __launch_bounds__(256) void k_transpose_cast(
    const float* __restrict__ src, unsigned short* __restrict__ dst) {
  __shared__ float tile[32][33];
  const int bx = blockIdx.x;
  const int n0 = (bx & 31) * 32, k0 = (bx >> 5) * 32;
  const int tx = threadIdx.x & 31, ty = threadIdx.x >> 5;
#pragma unroll
  for (int i = 0; i < 4; ++i)
    tile[ty + i * 8][tx] = src[(size_t)(k0 + ty + i * 8) * 1024 + n0 + tx];
  __syncthreads();
#pragma unroll
  for (int i = 0; i < 4; ++i)
    dst[(size_t)(n0 + ty + i * 8) * 1024 + k0 + tx] = f2bf(tile[tx][ty + i * 8]);
}

// ---------------------------------------------------------------------------
// Prep: cast x fp32 -> bf16 (vectorized 8/thread); also zero the 64 flags
// (REQUIRED each launch: graph replays leave flags at their final gen).
// ---------------------------------------------------------------------------
__global__ __launch_bounds__(256) void k_cast_x(
    const float* __restrict__ src, unsigned short* __restrict__ dst, int n8,
    int* __restrict__ flags) {
  if (blockIdx.x == 0 && threadIdx.x < 64)
    __hip_atomic_store(&flags[threadIdx.x * 64], 0, __ATOMIC_RELAXED,
                       __HIP_MEMORY_SCOPE_AGENT);
  int idx = blockIdx.x * 256 + threadIdx.x;
  if (idx >= n8) return;
  const floatx4* s = (const floatx4*)(src + (size_t)idx * 8);
  floatx4 a = s[0], b = s[1];
  short8 o;
  o[0] = (short)f2bf(a[0]); o[1] = (short)f2bf(a[1]);
  o[2] = (short)f2bf(a[2]); o[3] = (short)f2bf(a[3]);
  o[4] = (short)f2bf(b[0]); o[5] = (short)f2bf(b[1]);
  o[6] = (short)f2bf(b[2]); o[7] = (short)f2bf(b[3]);
  *(short8*)(dst + (size_t)idx * 8) = o;
}

// ---------------------------------------------------------------------------
// Phase 1 GEMM: gates[(s*64+b)][n] = x[b*512+s][k] * Wt[n][k]^T  (s-major out)
// ---------------------------------------------------------------------------
__global__ __launch_bounds__(256) void k_gemm_xw(
    const unsigned short* __restrict__ A,   // [32768][1024]
    const unsigned short* __restrict__ Bt,  // [4096][1024]
    unsigned short* __restrict__ C)         // [512 s][64 b][4096]
{
  __shared__ unsigned short As[128 * 32];
  __shared__ unsigned short Bs[128 * 32];
  const int bid = blockIdx.x;
  const int bm = bid & 255;
  const int bn = bid >> 8;
  const int m0 = bm * 128, n0 = bn * 128;
  const int tid = threadIdx.x;
  const int lane = tid & 63, wid = tid >> 6;

  const unsigned short* ga = A  + (size_t)(m0 + (tid >> 2)) * 1024 + (tid & 3) * 8;
  const unsigned short* gb = Bt + (size_t)(n0 + (tid >> 2)) * 1024 + (tid & 3) * 8;
  unsigned short* lA = As + wid * 512;
  unsigned short* lB = Bs + wid * 512;

  floatx4 acc[4][4] = {};
  const int wm = (wid >> 1) * 64, wn = (wid & 1) * 64;
  const int lr = lane & 15, lk = (lane >> 4) * 8;

  for (int k0 = 0; k0 < 1024; k0 += 32) {
    gload_lds16(ga + k0, lA);
    gload_lds16(ga + 64 * 1024 + k0, lA + 2048);
    gload_lds16(gb + k0, lB);
    gload_lds16(gb + 64 * 1024 + k0, lB + 2048);
    __syncthreads();
    short8 af[4], bfv[4];
#pragma unroll
    for (int mt = 0; mt < 4; ++mt)
      af[mt] = *(const short8*)(As + (wm + mt * 16 + lr) * 32 + lk);
#pragma unroll
    for (int nt = 0; nt < 4; ++nt)
      bfv[nt] = *(const short8*)(Bs + (wn + nt * 16 + lr) * 32 + lk);
#pragma unroll
    for (int mt = 0; mt < 4; ++mt)
#pragma unroll
      for (int nt = 0; nt < 4; ++nt)
        acc[mt][nt] = __builtin_amdgcn_mfma_f32_16x16x32_bf16(
            af[mt], bfv[nt], acc[mt][nt], 0, 0, 0);
    __syncthreads();
  }

  // epilogue: permute rows m=b*512+s -> out row s*64+b (s-major gates)
#pragma unroll
  for (int mt = 0; mt < 4; ++mt) {
    const int row = m0 + wm + mt * 16 + (lane >> 4) * 4;
#pragma unroll
    for (int r = 0; r < 4; ++r) {
      const int rr = row + r;
      unsigned short* cp = C + (size_t)((rr & 511) * 64 + (rr >> 9)) * 4096;
#pragma unroll
      for (int nt = 0; nt < 4; ++nt) {
        const int col = n0 + wn + nt * 16 + lr;
        cp[col] = f2bf(acc[mt][nt][r]);
      }
    }
  }
}

// ---------------------------------------------------------------------------
// Phase 2: recurrence. 64 persistent blocks x 512 threads (cooperative).
// Identical to R3 except the barrier is distributed-flag (no same-address
// atomic RMW, no polling storm on one line).
// ---------------------------------------------------------------------------
__global__ __launch_bounds__(512, 2) void k_recur64(
    const unsigned short* __restrict__ gates,  // [512 s][64 b][4096] bf16
    const unsigned short* __restrict__ Ut,     // [4][1024 n][1024 k] bf16
    const float* __restrict__ bF, const float* __restrict__ bI,
    const float* __restrict__ bO, const float* __restrict__ bC,
    unsigned short* __restrict__ hbuf,         // [2][64][1024] bf16
    int* __restrict__ flags,
    float* __restrict__ out)                   // ys | h | c
{
  __shared__ float part1[64][69];              // [gatecol_loc][batch], odd pad
  const int bid = blockIdx.x;                  // 0..63
  const int tid = threadIdx.x;                 // 0..511
  const int lane = tid & 63, w = tid >> 6;
  const int lr = lane & 15, lk = (lane >> 4) * 8;
  const int hcol0 = bid * 16;

  // Preload U fragments: wave w owns K-slice [w*128, w*128+128)
  short8 bfrag[4][4];                          // [gate n][kt]
#pragma unroll
  for (int n = 0; n < 4; ++n) {
    const unsigned short* up = Ut + ((size_t)n << 20) +
                               (size_t)(hcol0 + lr) * 1024 + w * 128 + lk;
#pragma unroll
    for (int kt = 0; kt < 4; ++kt)
      bfrag[n][kt] = *(const short8*)(up + kt * 32);
  }

  // Elementwise identity: thread -> (batch eb, col pair 2*ej, 2*ej+1)
  const int eb = tid >> 3, ej = tid & 7;
  const int hc0 = 2 * ej;                      // local col (even)
  const int gc = hcol0 + hc0;                  // global h col (even)
  float2 bias[4];
  bias[0] = *(const float2*)(bF + gc);
  bias[1] = *(const float2*)(bI + gc);
  bias[2] = *(const float2*)(bO + gc);
  bias[3] = *(const float2*)(bC + gc);

  // zero LDS accumulator + own slice of h_{-1} (buf 0)
  for (int i = tid; i < 64 * 69; i += 512) ((float*)part1)[i] = 0.0f;
  store_h4(hbuf + eb * 1024 + gc, 0u);

  float c0 = 0.f, c1 = 0.f, h0v = 0.f, h1v = 0.f;
  int gen = 1;
  grid_barrier(flags, gen++);

  // prefetch gates for s=0 (plain cached loads)
  unsigned int g_nxt[4];
#pragma unroll
  for (int g = 0; g < 4; ++g)
    g_nxt[g] = *(const unsigned int*)(gates + (size_t)eb * 4096 + g * 1024 + gc);

  for (int s = 0; s < SS; ++s) {
    const unsigned short* hp = hbuf + (s & 1) * 65536;
    unsigned short* hw = hbuf + ((s & 1) ^ 1) * 65536;
    unsigned int gcur[4] = { g_nxt[0], g_nxt[1], g_nxt[2], g_nxt[3] };

    // ---- MFMA over this wave's K-slice; A from L3 via relaxed atomics ----
    floatx4 acc[4][4] = {};                    // [mt][gate n]
    const unsigned short* hbase = hp + w * 128 + lk;
    short8 a0[4], a1[4];
#pragma unroll
    for (int mt = 0; mt < 4; ++mt)
      a0[mt] = load_h16(hbase + (size_t)(mt * 16 + lr) * 1024);
#pragma unroll
    for (int kt = 0; kt < 4; ++kt) {
      const short8* cur = (kt & 1) ? a1 : a0;
      short8* nxt = (kt & 1) ? a0 : a1;
      if (kt < 3) {
#pragma unroll
        for (int mt = 0; mt < 4; ++mt)
          nxt[mt] = load_h16(hbase + (kt + 1) * 32 +
                             (size_t)(mt * 16 + lr) * 1024);
      }
#pragma unroll
      for (int mt = 0; mt < 4; ++mt)
#pragma unroll
        for (int n = 0; n < 4; ++n)
          acc[mt][n] = __builtin_amdgcn_mfma_f32_16x16x32_bf16(
              cur[mt], bfrag[n][kt], acc[mt][n], 0, 0, 0);
    }

    // ---- cross-wave reduce: ds_add_f32 into part1 ----
    const int r0 = (lane >> 4) * 4;
#pragma unroll
    for (int mt = 0; mt < 4; ++mt)
#pragma unroll
      for (int n = 0; n < 4; ++n) {
        float* p = &part1[n * 16 + lr][mt * 16 + r0];
#pragma unroll
        for (int r = 0; r < 4; ++r) atomicAdd(p + r, acc[mt][n][r]);
      }

    // prefetch next step's gates (ride through the barrier in regs)
    const int sn = (s + 1 < SS) ? s + 1 : s;
#pragma unroll
    for (int g = 0; g < 4; ++g)
      g_nxt[g] = *(const unsigned int*)(gates + ((size_t)sn * 64 + eb) * 4096 +
                                        g * 1024 + gc);

    __syncthreads();  // all ds_adds visible

    // ---- gates + elementwise for 2 (b, col) pairs ----
    float pre0[4], pre1[4];
#pragma unroll
    for (int g = 0; g < 4; ++g) {
      pre0[g] = part1[g * 16 + hc0][eb] +
                bf2f((unsigned short)(gcur[g] & 0xffffu)) + bias[g].x;
      pre1[g] = part1[g * 16 + hc0 + 1][eb] +
                bf2f((unsigned short)(gcur[g] >> 16)) + bias[g].y;
    }
    float f0 = sigmoidf_(pre0[0]), f1 = sigmoidf_(pre1[0]);
    float i0 = sigmoidf_(pre0[1]), i1 = sigmoidf_(pre1[1]);
    float o0 = sigmoidf_(pre0[2]), o1 = sigmoidf_(pre1[2]);
    float q0 = tanhf_(pre0[3]),    q1 = tanhf_(pre1[3]);
    c0 = f0 * c0 + i0 * q0;  c1 = f1 * c1 + i1 * q1;
    h0v = o0 * tanhf_(c0);   h1v = o1 * tanhf_(c1);

    __syncthreads();  // reads of part1 done before re-zero
    for (int i = tid; i < 64 * 69; i += 512) ((float*)part1)[i] = 0.0f;

    // store h (bf16 pair, L2-bypass) + ys (fp32 pair, nontemporal)
    unsigned int hpack = (unsigned int)f2bf(h0v) |
                         ((unsigned int)f2bf(h1v) << 16);
    store_h4(hw + eb * 1024 + gc, hpack);
    float2 yv; yv.x = h0v; yv.y = h1v;
    __builtin_nontemporal_store(
        *(double*)&yv, (double*)(out + ((size_t)eb * 512 + s) * 1024 + gc));

    grid_barrier(flags, gen++);
  }

  // final (h, c)
  const size_t ys_sz = (size_t)BB * SS * HH;
  out[ys_sz + (size_t)eb * 1024 + gc]             = h0v;
  out[ys_sz + (size_t)eb * 1024 + gc + 1]         = h1v;
  out[ys_sz + 65536 + (size_t)eb * 1024 + gc]     = c0;
  out[ys_sz + 65536 + (size_t)eb * 1024 + gc + 1] = c1;
}

// ---------------------------------------------------------------------------
// Host launcher
// ---------------------------------------------------------------------------
extern "C" void kernel_launch(void* const* d_in, const int* in_sizes, int n_in,
                              void* d_out, int out_size, void* d_ws, size_t ws_size,
                              hipStream_t stream) {
  const float* x = (const float*)d_in[0];
  const float* w[4] = { (const float*)d_in[1], (const float*)d_in[4],
                        (const float*)d_in[7], (const float*)d_in[10] };
  const float* u[4] = { (const float*)d_in[2], (const float*)d_in[5],
                        (const float*)d_in[8], (const float*)d_in[11] };
  const float* b[4] = { (const float*)d_in[3], (const float*)d_in[6],
                        (const float*)d_in[9], (const float*)d_in[12] };

  const size_t OFF_WT = 0;                          //  8 MB  Wt bf16
  const size_t OFF_UT = 8u << 20;                   //  8 MB  Ut bf16
  const size_t OFF_XB = 16u << 20;                  // 64 MB  x  bf16
  const size_t OFF_GX = 80u << 20;                  // 256 MB gates bf16
  const size_t OFF_HB = (80u << 20) + (256u << 20); // 256 KB h dbuf
  const size_t OFF_BAR = OFF_HB + 2 * 65536 * 2;    // 64 flags * 256 B
  const size_t NEED = OFF_BAR + 64 * 64 * 4;
  if (ws_size < NEED) return;

  char* ws = (char*)d_ws;
  unsigned short* Wt = (unsigned short*)(ws + OFF_WT);
  unsigned short* Ut = (unsigned short*)(ws + OFF_UT);
  unsigned short* Xb = (unsigned short*)(ws + OFF_XB);
  unsigned short* Gx = (unsigned short*)(ws + OFF_GX);
  unsigned short* Hb = (unsigned short*)(ws + OFF_HB);
  int* Flags = (int*)(ws + OFF_BAR);

  for (int gi = 0; gi < 4; ++gi) {
    k_transpose_cast<<<1024, 256, 0, stream>>>(w[gi], Wt + (size_t)gi * 1024 * 1024);
    k_transpose_cast<<<1024, 256, 0, stream>>>(u[gi], Ut + (size_t)gi * 1024 * 1024);
  }
  k_cast_x<<<(MM * II / 8) / 256, 256, 0, stream>>>(x, Xb, MM * II / 8, Flags);
  k_gemm_xw<<<256 * 32, 256, 0, stream>>>(Xb, Wt, Gx);

  const unsigned short* gx_p = Gx;
  const unsigned short* ut_p = Ut;
  const float* b0 = b[0]; const float* b1 = b[1];
  const float* b2 = b[2]; const float* b3 = b[3];
  unsigned short* hb_p = Hb;
  int* flags_p = Flags;
  float* out_p = (float*)d_out;
  void* args[] = { (void*)&gx_p, (void*)&ut_p, (void*)&b0, (void*)&b1,
                   (void*)&b2, (void*)&b3, (void*)&hb_p, (void*)&flags_p,
                   (void*)&out_p };
  hipLaunchCooperativeKernel(k_recur64, dim3(NBLK), dim3(512), args, 0, stream);
}

// Round 5
// 24040.811 us; speedup vs baseline: 1.1006x; 1.0348x over previous
//
#include <hip/hip_runtime.h>
#include <stdint.h>

typedef __attribute__((ext_vector_type(8))) short short8;
typedef __attribute__((ext_vector_type(4))) float floatx4;

#define DI __device__ __forceinline__

// Problem dims
constexpr int BB = 64;          // batch
constexpr int SS = 512;         // seq len
constexpr int II = 1024;        // input size
constexpr int HH = 1024;        // hidden size
constexpr int MM = BB * SS;     // 32768 GEMM rows
constexpr int NBLK = 64;        // recurrence blocks

DI unsigned short f2bf(float f) {
  union { float f; unsigned int u; } v; v.f = f;
  unsigned int u = v.u;
  return (unsigned short)((u + 0x7FFFu + ((u >> 16) & 1u)) >> 16);  // RNE
}
DI float bf2f(unsigned short u) {
  union { unsigned int u; float f; } v; v.u = ((unsigned int)u) << 16;
  return v.f;
}
DI float sigmoidf_(float x) { return 1.0f / (1.0f + __expf(-x)); }
DI float tanhf_(float x)    { return 2.0f / (1.0f + __expf(-2.0f * x)) - 1.0f; }

DI void gload_lds16(const unsigned short* g, unsigned short* l) {
  typedef __attribute__((address_space(1))) const void gv_t;
  typedef __attribute__((address_space(3))) void lv_t;
  __builtin_amdgcn_global_load_lds((gv_t*)(uintptr_t)g, (lv_t*)(uintptr_t)l, 16, 0, 0);
}

// h WRITES: relaxed agent atomic store — completes at the coherent point (L3),
// no wbL2 needed, acked before the barrier flag via the vmcnt(0) drain.
DI void store_h4(unsigned short* p, unsigned int v) {
  __hip_atomic_store((unsigned int*)p, v, __ATOMIC_RELAXED,
                     __HIP_MEMORY_SCOPE_AGENT);
}
// h READS are PLAIN CACHED LOADS (the R5 change). Safe because each h slot
// address is written exactly once per launch and only read after the barrier
// that orders it (monotonic slot rotation) — no stale line can exist within
// a launch; cross-replay staleness is killed by one entry acquire-fence.

// Distributed-flag grid barrier (R4): block i owns flags[i*64]; wave 0
// gathers all 64 flags one-per-lane. No same-address RMW, no fences.
DI void grid_barrier(int* flags, int gen) {
  __syncthreads();                 // all waves' stores drained (vmcnt 0)
  const int t = threadIdx.x;
  if (t < 64) {
    if (t == (int)blockIdx.x)
      __hip_atomic_store(&flags[t * 64], gen, __ATOMIC_RELAXED,
                         __HIP_MEMORY_SCOPE_AGENT);
    while (__hip_atomic_load(&flags[t * 64], __ATOMIC_RELAXED,
                             __HIP_MEMORY_SCOPE_AGENT) < gen) {
    }
  }
  __syncthreads();
}

// ---------------------------------------------------------------------------
// Prep: transpose+cast one fp32 [1024(k)][1024(n)] matrix -> bf16 [n][k]
// ---------------------------------------------------------------------------
__global__ __launch_bounds__(256) void k_transpose_cast(
    const float* __restrict__ src, unsigned short* __restrict__ dst) {
  __shared__ float tile[32][33];
  const int bx = blockIdx.x;
  const int n0 = (bx & 31) * 32, k0 = (bx >> 5) * 32;
  const int tx = threadIdx.x & 31, ty = threadIdx.x >> 5;
#pragma unroll
  for (int i = 0; i < 4; ++i)
    tile[ty + i * 8][tx] = src[(size_t)(k0 + ty + i * 8) * 1024 + n0 + tx];
  __syncthreads();
#pragma unroll
  for (int i = 0; i < 4; ++i)
    dst[(size_t)(n0 + ty + i * 8) * 1024 + k0 + tx] = f2bf(tile[tx][ty + i * 8]);
}

// ---------------------------------------------------------------------------
// Prep: cast x fp32 -> bf16 (vectorized 8/thread); also zero the 64 flags
// (REQUIRED each launch: graph replays leave flags at their final gen).
// ---------------------------------------------------------------------------
__global__ __launch_bounds__(256) void k_cast_x(
    const float* __restrict__ src, unsigned short* __restrict__ dst, int n8,
    int* __restrict__ flags) {
  if (blockIdx.x == 0 && threadIdx.x < 64)
    __hip_atomic_store(&flags[threadIdx.x * 64], 0, __ATOMIC_RELAXED,
                       __HIP_MEMORY_SCOPE_AGENT);
  int idx = blockIdx.x * 256 + threadIdx.x;
  if (idx >= n8) return;
  const floatx4* s = (const floatx4*)(src + (size_t)idx * 8);
  floatx4 a = s[0], b = s[1];
  short8 o;
  o[0] = (short)f2bf(a[0]); o[1] = (short)f2bf(a[1]);
  o[2] = (short)f2bf(a[2]); o[3] = (short)f2bf(a[3]);
  o[4] = (short)f2bf(b[0]); o[5] = (short)f2bf(b[1]);
  o[6] = (short)f2bf(b[2]); o[7] = (short)f2bf(b[3]);
  *(short8*)(dst + (size_t)idx * 8) = o;
}

// ---------------------------------------------------------------------------
// Phase 1 GEMM: gates[(s*64+b)][n] = x[b*512+s][k] * Wt[n][k]^T  (s-major out)
// ---------------------------------------------------------------------------
__global__ __launch_bounds__(256) void k_gemm_xw(
    const unsigned short* __restrict__ A,   // [32768][1024]
    const unsigned short* __restrict__ Bt,  // [4096][1024]
    unsigned short* __restrict__ C)         // [512 s][64 b][4096]
{
  __shared__ unsigned short As[128 * 32];
  __shared__ unsigned short Bs[128 * 32];
  const int bid = blockIdx.x;
  const int bm = bid & 255;
  const int bn = bid >> 8;
  const int m0 = bm * 128, n0 = bn * 128;
  const int tid = threadIdx.x;
  const int lane = tid & 63, wid = tid >> 6;

  const unsigned short* ga = A  + (size_t)(m0 + (tid >> 2)) * 1024 + (tid & 3) * 8;
  const unsigned short* gb = Bt + (size_t)(n0 + (tid >> 2)) * 1024 + (tid & 3) * 8;
  unsigned short* lA = As + wid * 512;
  unsigned short* lB = Bs + wid * 512;

  floatx4 acc[4][4] = {};
  const int wm = (wid >> 1) * 64, wn = (wid & 1) * 64;
  const int lr = lane & 15, lk = (lane >> 4) * 8;

  for (int k0 = 0; k0 < 1024; k0 += 32) {
    gload_lds16(ga + k0, lA);
    gload_lds16(ga + 64 * 1024 + k0, lA + 2048);
    gload_lds16(gb + k0, lB);
    gload_lds16(gb + 64 * 1024 + k0, lB + 2048);
    __syncthreads();
    short8 af[4], bfv[4];
#pragma unroll
    for (int mt = 0; mt < 4; ++mt)
      af[mt] = *(const short8*)(As + (wm + mt * 16 + lr) * 32 + lk);
#pragma unroll
    for (int nt = 0; nt < 4; ++nt)
      bfv[nt] = *(const short8*)(Bs + (wn + nt * 16 + lr) * 32 + lk);
#pragma unroll
    for (int mt = 0; mt < 4; ++mt)
#pragma unroll
      for (int nt = 0; nt < 4; ++nt)
        acc[mt][nt] = __builtin_amdgcn_mfma_f32_16x16x32_bf16(
            af[mt], bfv[nt], acc[mt][nt], 0, 0, 0);
    __syncthreads();
  }

  // epilogue: permute rows m=b*512+s -> out row s*64+b (s-major gates)
#pragma unroll
  for (int mt = 0; mt < 4; ++mt) {
    const int row = m0 + wm + mt * 16 + (lane >> 4) * 4;
#pragma unroll
    for (int r = 0; r < 4; ++r) {
      const int rr = row + r;
      unsigned short* cp = C + (size_t)((rr & 511) * 64 + (rr >> 9)) * 4096;
#pragma unroll
      for (int nt = 0; nt < 4; ++nt) {
        const int col = n0 + wn + nt * 16 + lr;
        cp[col] = f2bf(acc[mt][nt][r]);
      }
    }
  }
}

// ---------------------------------------------------------------------------
// Phase 2: recurrence. 64 persistent blocks x 512 threads (cooperative).
// R5: h reads are plain cached loads from a ROTATING slot history (hist
// reuses the dead Xb region: 512 slots x 128 KB; slot 512 in hlast).
// h writes remain relaxed L3 atomic stores. One acquire fence at entry.
// ---------------------------------------------------------------------------
__global__ __launch_bounds__(512, 2) void k_recur64(
    const unsigned short* __restrict__ gates,  // [512 s][64 b][4096] bf16
    const unsigned short* __restrict__ Ut,     // [4][1024 n][1024 k] bf16
    const float* __restrict__ bF, const float* __restrict__ bI,
    const float* __restrict__ bO, const float* __restrict__ bC,
    unsigned short* __restrict__ hist,         // [512][64][1024] bf16 (slots 0..511)
    unsigned short* __restrict__ hlast,        // slot 512
    int* __restrict__ flags,
    float* __restrict__ out)                   // ys | h | c
{
  // Invalidate L1+L2 once per launch: kills cross-replay stale lines for the
  // rotating h slots. (R1/R2 paid this PER STEP; here it's once.)
  __builtin_amdgcn_fence(__ATOMIC_ACQUIRE, "agent");

  __shared__ float part1[64][69];              // [gatecol_loc][batch], odd pad
  const int bid = blockIdx.x;                  // 0..63
  const int tid = threadIdx.x;                 // 0..511
  const int lane = tid & 63, w = tid >> 6;
  const int lr = lane & 15, lk = (lane >> 4) * 8;
  const int hcol0 = bid * 16;

  // Preload U fragments: wave w owns K-slice [w*128, w*128+128)
  short8 bfrag[4][4];                          // [gate n][kt]
#pragma unroll
  for (int n = 0; n < 4; ++n) {
    const unsigned short* up = Ut + ((size_t)n << 20) +
                               (size_t)(hcol0 + lr) * 1024 + w * 128 + lk;
#pragma unroll
    for (int kt = 0; kt < 4; ++kt)
      bfrag[n][kt] = *(const short8*)(up + kt * 32);
  }

  // Elementwise identity: thread -> (batch eb, col pair 2*ej, 2*ej+1)
  const int eb = tid >> 3, ej = tid & 7;
  const int hc0 = 2 * ej;                      // local col (even)
  const int gc = hcol0 + hc0;                  // global h col (even)
  float2 bias[4];
  bias[0] = *(const float2*)(bF + gc);
  bias[1] = *(const float2*)(bI + gc);
  bias[2] = *(const float2*)(bO + gc);
  bias[3] = *(const float2*)(bC + gc);

  // zero LDS accumulator + own slice of h_{-1} (slot 0)
  for (int i = tid; i < 64 * 69; i += 512) ((float*)part1)[i] = 0.0f;
  store_h4(hist + eb * 1024 + gc, 0u);

  float c0 = 0.f, c1 = 0.f, h0v = 0.f, h1v = 0.f;
  int gen = 1;
  grid_barrier(flags, gen++);

  // prefetch gates for s=0 (plain cached loads)
  unsigned int g_nxt[4];
#pragma unroll
  for (int g = 0; g < 4; ++g)
    g_nxt[g] = *(const unsigned int*)(gates + (size_t)eb * 4096 + g * 1024 + gc);

  for (int s = 0; s < SS; ++s) {
    // ys store for step s-1: post-barrier, so its HBM ack overlaps this
    // whole step instead of stalling the pre-arrive vmcnt drain.
    if (s > 0) {
      float2 yv; yv.x = h0v; yv.y = h1v;
      __builtin_nontemporal_store(
          *(double*)&yv,
          (double*)(out + ((size_t)eb * 512 + (s - 1)) * 1024 + gc));
    }

    const unsigned short* hp = hist + (size_t)s * 65536;          // read slot s
    unsigned short* hw = (s + 1 < 512) ? hist + (size_t)(s + 1) * 65536
                                       : hlast;                   // write slot s+1
    unsigned int gcur[4] = { g_nxt[0], g_nxt[1], g_nxt[2], g_nxt[3] };

    // ---- issue all h loads (PLAIN cached, fully pipelined) ----
    const unsigned short* hbase = hp + w * 128 + lk;
    short8 a[4][4];                            // [kt][mt]
#pragma unroll
    for (int kt = 0; kt < 4; ++kt)
#pragma unroll
      for (int mt = 0; mt < 4; ++mt)
        a[kt][mt] = *(const short8*)(hbase + kt * 32 +
                                     (size_t)(mt * 16 + lr) * 1024);

    // gates prefetch for next step: issued now so it completes under
    // MFMA + reduce, well before the barrier drain.
    const int sn = (s + 1 < SS) ? s + 1 : s;
#pragma unroll
    for (int g = 0; g < 4; ++g)
      g_nxt[g] = *(const unsigned int*)(gates + ((size_t)sn * 64 + eb) * 4096 +
                                        g * 1024 + gc);

    // ---- MFMA over this wave's K-slice ----
    floatx4 acc[4][4] = {};                    // [mt][gate n]
#pragma unroll
    for (int kt = 0; kt < 4; ++kt)
#pragma unroll
      for (int mt = 0; mt < 4; ++mt)
#pragma unroll
        for (int n = 0; n < 4; ++n)
          acc[mt][n] = __builtin_amdgcn_mfma_f32_16x16x32_bf16(
              a[kt][mt], bfrag[n][kt], acc[mt][n], 0, 0, 0);

    // ---- cross-wave reduce: ds_add_f32 into part1 ----
    const int r0 = (lane >> 4) * 4;
#pragma unroll
    for (int mt = 0; mt < 4; ++mt)
#pragma unroll
      for (int n = 0; n < 4; ++n) {
        float* p = &part1[n * 16 + lr][mt * 16 + r0];
#pragma unroll
        for (int r = 0; r < 4; ++r) atomicAdd(p + r, acc[mt][n][r]);
      }

    __syncthreads();  // all ds_adds visible

    // ---- gates + elementwise for 2 (b, col) pairs ----
    float pre0[4], pre1[4];
#pragma unroll
    for (int g = 0; g < 4; ++g) {
      pre0[g] = part1[g * 16 + hc0][eb] +
                bf2f((unsigned short)(gcur[g] & 0xffffu)) + bias[g].x;
      pre1[g] = part1[g * 16 + hc0 + 1][eb] +
                bf2f((unsigned short)(gcur[g] >> 16)) + bias[g].y;
    }
    float f0 = sigmoidf_(pre0[0]), f1 = sigmoidf_(pre1[0]);
    float i0 = sigmoidf_(pre0[1]), i1 = sigmoidf_(pre1[1]);
    float o0 = sigmoidf_(pre0[2]), o1 = sigmoidf_(pre1[2]);
    float q0 = tanhf_(pre0[3]),    q1 = tanhf_(pre1[3]);
    c0 = f0 * c0 + i0 * q0;  c1 = f1 * c1 + i1 * q1;
    h0v = o0 * tanhf_(c0);   h1v = o1 * tanhf_(c1);

    __syncthreads();  // reads of part1 done before re-zero
    for (int i = tid; i < 64 * 69; i += 512) ((float*)part1)[i] = 0.0f;

    // store h (bf16 pair) to slot s+1 at L3
    unsigned int hpack = (unsigned int)f2bf(h0v) |
                         ((unsigned int)f2bf(h1v) << 16);
    store_h4(hw + eb * 1024 + gc, hpack);

    grid_barrier(flags, gen++);
  }

  // final ys (s=511) + (h, c)
  {
    float2 yv; yv.x = h0v; yv.y = h1v;
    __builtin_nontemporal_store(
        *(double*)&yv, (double*)(out + ((size_t)eb * 512 + 511) * 1024 + gc));
  }
  const size_t ys_sz = (size_t)BB * SS * HH;
  out[ys_sz + (size_t)eb * 1024 + gc]             = h0v;
  out[ys_sz + (size_t)eb * 1024 + gc + 1]         = h1v;
  out[ys_sz + 65536 + (size_t)eb * 1024 + gc]     = c0;
  out[ys_sz + 65536 + (size_t)eb * 1024 + gc + 1] = c1;
}

// ---------------------------------------------------------------------------
// Host launcher
// ---------------------------------------------------------------------------
extern "C" void kernel_launch(void* const* d_in, const int* in_sizes, int n_in,
                              void* d_out, int out_size, void* d_ws, size_t ws_size,
                              hipStream_t stream) {
  const float* x = (const float*)d_in[0];
  const float* w[4] = { (const float*)d_in[1], (const float*)d_in[4],
                        (const float*)d_in[7], (const float*)d_in[10] };
  const float* u[4] = { (const float*)d_in[2], (const float*)d_in[5],
                        (const float*)d_in[8], (const float*)d_in[11] };
  const float* b[4] = { (const float*)d_in[3], (const float*)d_in[6],
                        (const float*)d_in[9], (const float*)d_in[12] };

  const size_t OFF_WT = 0;                          //  8 MB  Wt bf16
  const size_t OFF_UT = 8u << 20;                   //  8 MB  Ut bf16
  const size_t OFF_XB = 16u << 20;                  // 64 MB  x bf16, then h hist
  const size_t OFF_GX = 80u << 20;                  // 256 MB gates bf16
  const size_t OFF_HB = (80u << 20) + (256u << 20); // 256 KB: h slot 512
  const size_t OFF_BAR = OFF_HB + 2 * 65536 * 2;    // 64 flags * 256 B
  const size_t NEED = OFF_BAR + 64 * 64 * 4;
  if (ws_size < NEED) return;

  char* ws = (char*)d_ws;
  unsigned short* Wt = (unsigned short*)(ws + OFF_WT);
  unsigned short* Ut = (unsigned short*)(ws + OFF_UT);
  unsigned short* Xb = (unsigned short*)(ws + OFF_XB);  // x, then h history
  unsigned short* Gx = (unsigned short*)(ws + OFF_GX);
  unsigned short* Hl = (unsigned short*)(ws + OFF_HB);
  int* Flags = (int*)(ws + OFF_BAR);

  for (int gi = 0; gi < 4; ++gi) {
    k_transpose_cast<<<1024, 256, 0, stream>>>(w[gi], Wt + (size_t)gi * 1024 * 1024);
    k_transpose_cast<<<1024, 256, 0, stream>>>(u[gi], Ut + (size_t)gi * 1024 * 1024);
  }
  k_cast_x<<<(MM * II / 8) / 256, 256, 0, stream>>>(x, Xb, MM * II / 8, Flags);
  k_gemm_xw<<<256 * 32, 256, 0, stream>>>(Xb, Wt, Gx);

  const unsigned short* gx_p = Gx;
  const unsigned short* ut_p = Ut;
  const float* b0 = b[0]; const float* b1 = b[1];
  const float* b2 = b[2]; const float* b3 = b[3];
  unsigned short* hist_p = Xb;   // x is dead after k_gemm_xw; reuse as h hist
  unsigned short* hlast_p = Hl;
  int* flags_p = Flags;
  float* out_p = (float*)d_out;
  void* args[] = { (void*)&gx_p, (void*)&ut_p, (void*)&b0, (void*)&b1,
                   (void*)&b2, (void*)&b3, (void*)&hist_p, (void*)&hlast_p,
                   (void*)&flags_p, (void*)&out_p };
  hipLaunchCooperativeKernel(k_recur64, dim3(NBLK), dim3(512), args, 0, stream);
}